// Round 3
// baseline (978.685 us; speedup 1.0000x reference)
//
#include <hip/hip_runtime.h>
#include <hip/hip_bf16.h>
#include <stdint.h>

// Problem constants
#define B_    256
#define LS_   1024
#define LW_   1024
#define LV_   1024
#define M_    16
#define D_    5120
#define H_    2048
#define ROWS  4096   // B*M
#define N1    4096   // H (eta) + H (rho) fused

typedef __hip_bfloat16 bf16;
typedef __bf16 bf16x8 __attribute__((ext_vector_type(8)));
typedef float f32x4 __attribute__((ext_vector_type(4)));

#define MEMF() asm volatile("" ::: "memory")
#define BARR() do { MEMF(); __builtin_amdgcn_s_barrier(); MEMF(); } while (0)
#define LGKM0() asm volatile("s_waitcnt lgkmcnt(0)" ::: "memory")
#define VMCNT8() asm volatile("s_waitcnt vmcnt(8)" ::: "memory")
#define VMCNT0() asm volatile("s_waitcnt vmcnt(0)" ::: "memory")

// ---------------------------------------------------------------------------
// async global->LDS, 16B per lane (HW: wave-uniform LDS base + lane*16).
__device__ __forceinline__ void gld_lds16(const void* g, void* l) {
  auto gp = (const __attribute__((address_space(1))) uint32_t*)(uintptr_t)g;
  auto lp = (__attribute__((address_space(3))) uint32_t*)(uint32_t)(uintptr_t)l;
  __builtin_amdgcn_global_load_lds(gp, lp, 16, 0, 0);
}

// ---------------------------------------------------------------------------
__global__ void sfeat_kernel(const float* __restrict__ phi, bf16* __restrict__ sfeat) {
  int i = blockIdx.x * blockDim.x + threadIdx.x;
  int b = i >> 10, l = i & 1023;
  float p = phi[i];
  float s, c;
  sincosf(p, &s, &c);
  sfeat[b * 2048 + l]        = __float2bfloat16(0.03125f * c);
  sfeat[b * 2048 + 1024 + l] = __float2bfloat16(0.03125f * s);
}

// ---------------------------------------------------------------------------
__global__ void transpose_bf16_kernel(const float* __restrict__ in, bf16* __restrict__ out,
                                      int R, int C) {
  __shared__ float tile[32][33];
  int c0 = blockIdx.x * 32, r0 = blockIdx.y * 32;
  int tx = threadIdx.x, ty = threadIdx.y;   // 32 x 8
#pragma unroll
  for (int i = 0; i < 32; i += 8)
    tile[ty + i][tx] = in[(size_t)(r0 + ty + i) * C + (c0 + tx)];
  __syncthreads();
#pragma unroll
  for (int i = 0; i < 32; i += 8)
    out[(size_t)(c0 + ty + i) * R + (r0 + tx)] = __float2bfloat16(tile[tx][ty + i]);
}

// ---------------------------------------------------------------------------
__global__ void build_x_kernel(const bf16* __restrict__ sfeat,
                               const float* __restrict__ wr_, const float* __restrict__ wi_,
                               const float* __restrict__ vM, bf16* __restrict__ X) {
  int row = blockIdx.x;
  int b = row >> 4, m = row & 15;
  bf16* xr = X + (size_t)row * D_;
  const bf16* sf = sfeat + (size_t)b * 2048;
  for (int c = threadIdx.x; c < 2048; c += 256) xr[c] = sf[c];
  const float* wrb = wr_ + (size_t)b * (LW_ * M_) + m;
  for (int c = threadIdx.x; c < 1024; c += 256) xr[2048 + c] = __float2bfloat16(wrb[c * 16]);
  const float* wib = wi_ + (size_t)b * (LW_ * M_) + m;
  for (int c = threadIdx.x; c < 1024; c += 256) xr[3072 + c] = __float2bfloat16(wib[c * 16]);
  for (int c = threadIdx.x; c < 1024; c += 256) xr[4096 + c] = __float2bfloat16(vM[c * 16 + m]);
}

// ---------------------------------------------------------------------------
// GEMM1: 256x256 tile, BK=64, 8 waves (2Mx4N), balanced 4-phase schedule with
// one-tile-ahead B-fragment pre-read. Reads/wave per phase: 8/8/4/4 so the
// LDS wait of each phase hides under the previous phase's MFMA drain.
__global__ void __launch_bounds__(512, 2)
gemm1_256_kernel(const bf16* __restrict__ A, const bf16* __restrict__ Bt,
                 const float* __restrict__ bias0, const float* __restrict__ bias1,
                 bf16* __restrict__ outH) {
  extern __shared__ __align__(16) char smem[];
  constexpr int LDA = D_;        // 5120 (both operands)
  constexpr int NT  = D_ / 64;   // 80 K-tiles (even)

  const int tid  = threadIdx.x;
  const int lane = tid & 63;
  const int wave = tid >> 6;
  const int wr = wave >> 2, wc = wave & 3;   // 2 x 4 wave grid
  const int fr = lane & 15, fq = lane >> 4;
  const int row0 = blockIdx.y * 256, col0 = blockIdx.x * 256;

  // staging: thread covers (local row rl, slot sl); global col pre-swizzled
  const int rl = tid >> 3, sl = tid & 7;
  const int srcCol = ((sl ^ (rl & 7)) << 4);
  const char* Ab = (const char*)A;
  const char* Bb = (const char*)Bt;

  // ds_read fragment offsets (swizzled slot)
  const int xr  = fr & 7;
  const int sA0 = ((fq ^ xr) << 4);
  const int sA1 = (((4 + fq) ^ xr) << 4);
  const int aBase = (wr * 128 + fr) << 7;
  const int bBase = 32768 + ((wc * 64 + fr) << 7);

  char* buf0 = smem;
  char* buf1 = smem + 65536;

  auto stage = [&](const char* gb, int grow0, int kt, int p, char* dst, int dOff) {
    const char* g = gb + ((size_t)(grow0 + p * 64 + rl) * LDA + (size_t)kt * 64) * 2 + srcCol;
    gld_lds16(g, dst + dOff + p * 8192 + tid * 16);
  };

  f32x4 acc[8][4] = {};
  bf16x8 bX[4][2], bY[4][2];

  // prologue: tile0 -> buf0, tile1 -> buf1; pre-read B(t0) into bX
#pragma unroll
  for (int p = 0; p < 4; ++p) stage(Ab, row0, 0, p, buf0, 0);
#pragma unroll
  for (int p = 0; p < 4; ++p) stage(Bb, col0, 0, p, buf0, 32768);
#pragma unroll
  for (int p = 0; p < 4; ++p) stage(Ab, row0, 1, p, buf1, 0);
#pragma unroll
  for (int p = 0; p < 4; ++p) stage(Bb, col0, 1, p, buf1, 32768);
  VMCNT8();   // t0 landed; t1's 8 still in flight
  BARR();
#pragma unroll
  for (int n = 0; n < 4; ++n) {
    bX[n][0] = *(const bf16x8*)(buf0 + bBase + n * 2048 + sA0);
    bX[n][1] = *(const bf16x8*)(buf0 + bBase + n * 2048 + sA1);
  }

  // one tile: read A frags of tile T from cur; MFMA with bC (pre-read);
  // pre-read B frags of tile T+1 from nxt into bN; stage tile T+2 into cur.
  auto iter = [&](int T, char* cur, char* nxt,
                  bf16x8 (&bC)[4][2], bf16x8 (&bN)[4][2]) {
    const bool rb = (T + 1 < NT);
    const bool pf = (T + 2 < NT);
    bf16x8 aLo[4][2], aHi[4][2];

    // ---- P1: read a0-3 (8); MFMA Q00 = m0-3 x n0-1
#pragma unroll
    for (int m = 0; m < 4; ++m) {
      aLo[m][0] = *(const bf16x8*)(cur + aBase + m * 2048 + sA0);
      aLo[m][1] = *(const bf16x8*)(cur + aBase + m * 2048 + sA1);
    }
    BARR(); LGKM0();
    __builtin_amdgcn_s_setprio(1);
#pragma unroll
    for (int m = 0; m < 4; ++m)
#pragma unroll
      for (int n = 0; n < 2; ++n) {
        acc[m][n] = __builtin_amdgcn_mfma_f32_16x16x32_bf16(aLo[m][0], bC[n][0], acc[m][n], 0, 0, 0);
        acc[m][n] = __builtin_amdgcn_mfma_f32_16x16x32_bf16(aLo[m][1], bC[n][1], acc[m][n], 0, 0, 0);
      }
    __builtin_amdgcn_s_setprio(0);
    BARR();

    // ---- P2: read a4-7 (8); MFMA Q10 = m4-7 x n0-1; vmcnt(0) retires tile T+1
#pragma unroll
    for (int m = 0; m < 4; ++m) {
      aHi[m][0] = *(const bf16x8*)(cur + aBase + (m + 4) * 2048 + sA0);
      aHi[m][1] = *(const bf16x8*)(cur + aBase + (m + 4) * 2048 + sA1);
    }
    BARR(); LGKM0();
    __builtin_amdgcn_s_setprio(1);
#pragma unroll
    for (int m = 0; m < 4; ++m)
#pragma unroll
      for (int n = 0; n < 2; ++n) {
        acc[m + 4][n] = __builtin_amdgcn_mfma_f32_16x16x32_bf16(aHi[m][0], bC[n][0], acc[m + 4][n], 0, 0, 0);
        acc[m + 4][n] = __builtin_amdgcn_mfma_f32_16x16x32_bf16(aHi[m][1], bC[n][1], acc[m + 4][n], 0, 0, 0);
      }
    __builtin_amdgcn_s_setprio(0);
    VMCNT0();   // tile T+1's loads (issued 4 phases ago) -> landed; ~free
    BARR();

    // ---- P3: read b01' of T+1 (4, nxt); stage A(T+2) -> cur; MFMA Q01
    if (rb) {
#pragma unroll
      for (int n = 0; n < 2; ++n) {
        bN[n][0] = *(const bf16x8*)(nxt + bBase + n * 2048 + sA0);
        bN[n][1] = *(const bf16x8*)(nxt + bBase + n * 2048 + sA1);
      }
    }
    if (pf) {
#pragma unroll
      for (int p = 0; p < 4; ++p) stage(Ab, row0, T + 2, p, cur, 0);
    }
    BARR(); LGKM0();
    __builtin_amdgcn_s_setprio(1);
#pragma unroll
    for (int m = 0; m < 4; ++m)
#pragma unroll
      for (int n = 0; n < 2; ++n) {
        acc[m][n + 2] = __builtin_amdgcn_mfma_f32_16x16x32_bf16(aLo[m][0], bC[n + 2][0], acc[m][n + 2], 0, 0, 0);
        acc[m][n + 2] = __builtin_amdgcn_mfma_f32_16x16x32_bf16(aLo[m][1], bC[n + 2][1], acc[m][n + 2], 0, 0, 0);
      }
    __builtin_amdgcn_s_setprio(0);
    BARR();

    // ---- P4: read b23' of T+1 (4, nxt); stage B(T+2) -> cur; MFMA Q11
    if (rb) {
#pragma unroll
      for (int n = 0; n < 2; ++n) {
        bN[n + 2][0] = *(const bf16x8*)(nxt + bBase + (n + 2) * 2048 + sA0);
        bN[n + 2][1] = *(const bf16x8*)(nxt + bBase + (n + 2) * 2048 + sA1);
      }
    }
    if (pf) {
#pragma unroll
      for (int p = 0; p < 4; ++p) stage(Bb, col0, T + 2, p, cur, 32768);
    }
    BARR(); LGKM0();
    __builtin_amdgcn_s_setprio(1);
#pragma unroll
    for (int m = 0; m < 4; ++m)
#pragma unroll
      for (int n = 0; n < 2; ++n) {
        acc[m + 4][n + 2] = __builtin_amdgcn_mfma_f32_16x16x32_bf16(aHi[m][0], bC[n + 2][0], acc[m + 4][n + 2], 0, 0, 0);
        acc[m + 4][n + 2] = __builtin_amdgcn_mfma_f32_16x16x32_bf16(aHi[m][1], bC[n + 2][1], acc[m + 4][n + 2], 0, 0, 0);
      }
    __builtin_amdgcn_s_setprio(0);
    BARR();
  };

  for (int t = 0; t < NT; t += 2) {
    iter(t,     buf0, buf1, bX, bY);
    iter(t + 1, buf1, buf0, bY, bX);
  }

  // epilogue: bias + relu -> bf16
#pragma unroll
  for (int m = 0; m < 8; ++m) {
#pragma unroll
    for (int n = 0; n < 4; ++n) {
      const int c = col0 + wc * 64 + n * 16 + fr;
      const float bias = (c < H_) ? bias0[c] : bias1[c - H_];
#pragma unroll
      for (int j = 0; j < 4; ++j) {
        const int r = row0 + wr * 128 + m * 16 + fq * 4 + j;
        float v = acc[m][n][j] + bias;
        outH[(size_t)r * N1 + c] = __float2bfloat16(v > 0.f ? v : 0.f);
      }
    }
  }
}

// ---------------------------------------------------------------------------
// 128x128 m97-style GEMM (GEMM2): out1 scatter = eta_M^T
__global__ void __launch_bounds__(256)
gemm2_bt_kernel(const bf16* __restrict__ A, int lda,
                const bf16* __restrict__ Bt, int ldb, int K,
                const float* __restrict__ bias0, float* __restrict__ outS) {
  __shared__ __align__(16) bf16 As[128 * 32];
  __shared__ __align__(16) bf16 Bs[128 * 32];

  const int tid  = threadIdx.x;
  const int lane = tid & 63;
  const int wave = tid >> 6;
  const int wr = wave >> 1, wc = wave & 1;
  const int fr = lane & 15;
  const int fq = lane >> 4;
  const int row0 = blockIdx.y * 128;
  const int col0 = blockIdx.x * 128;

  const int li0 = tid, li1 = tid + 256;
  const int r0s = li0 >> 2, c0s = (li0 & 3) << 3;
  const int r1s = li1 >> 2, c1s = (li1 & 3) << 3;

  f32x4 acc[4][4] = {};

  for (int k0 = 0; k0 < K; k0 += 32) {
    gld_lds16(A  + (size_t)(row0 + r0s) * lda + k0 + c0s, &As[li0 * 8]);
    gld_lds16(Bt + (size_t)(col0 + r0s) * ldb + k0 + c0s, &Bs[li0 * 8]);
    gld_lds16(A  + (size_t)(row0 + r1s) * lda + k0 + c1s, &As[li1 * 8]);
    gld_lds16(Bt + (size_t)(col0 + r1s) * ldb + k0 + c1s, &Bs[li1 * 8]);
    __syncthreads();

    bf16x8 a[4], b[4];
#pragma unroll
    for (int m = 0; m < 4; ++m)
      a[m] = *reinterpret_cast<const bf16x8*>(&As[(wr * 64 + m * 16 + fr) * 32 + fq * 8]);
#pragma unroll
    for (int n = 0; n < 4; ++n)
      b[n] = *reinterpret_cast<const bf16x8*>(&Bs[(wc * 64 + n * 16 + fr) * 32 + fq * 8]);
#pragma unroll
    for (int m = 0; m < 4; ++m)
#pragma unroll
      for (int n = 0; n < 4; ++n)
        acc[m][n] = __builtin_amdgcn_mfma_f32_16x16x32_bf16(a[m], b[n], acc[m][n], 0, 0, 0);
    __syncthreads();
  }

#pragma unroll
  for (int m = 0; m < 4; ++m) {
#pragma unroll
    for (int n = 0; n < 4; ++n) {
      const int c = col0 + wc * 64 + n * 16 + fr;
      const float bias = bias0[c];
#pragma unroll
      for (int j = 0; j < 4; ++j) {
        const int r = row0 + wr * 64 + m * 16 + fq * 4 + j;
        outS[((size_t)(r >> 4)) * (LS_ * M_) + (size_t)c * M_ + (r & 15)] = acc[m][n][j] + bias;
      }
    }
  }
}

// ---------------------------------------------------------------------------
__global__ void rho_kernel(const bf16* __restrict__ h, const float* __restrict__ w2r,
                           const float* __restrict__ b2r, float* __restrict__ rho) {
  int r = blockIdx.x;
  int t = threadIdx.x;
  int lane = t & 63, wave = t >> 6;
  const bf16* hr = h + (size_t)r * N1 + H_;
  float s = 0.f;
#pragma unroll
  for (int j = 0; j < 8; ++j)
    s += __bfloat162float(hr[t * 8 + j]) * w2r[t * 8 + j];
#pragma unroll
  for (int off = 32; off > 0; off >>= 1) s += __shfl_down(s, off);
  __shared__ float ws4[4];
  if (lane == 0) ws4[wave] = s;
  __syncthreads();
  if (t == 0) rho[r] = ws4[0] + ws4[1] + ws4[2] + ws4[3] + b2r[0];
}

// ---------------------------------------------------------------------------
__global__ void finalize_kernel(const float* __restrict__ phi, const float* __restrict__ rho,
                                const float* __restrict__ etaMT, float* __restrict__ out0) {
  int i = blockIdx.x * blockDim.x + threadIdx.x;
  int b = i >> 10;
  const float* em = etaMT + (size_t)i * 16;
  const float* rb = rho + b * 16;
  float s = 0.f;
#pragma unroll
  for (int m = 0; m < 16; ++m) s += rb[m] * em[m];
  out0[i] = phi[i] - s;
}

// ---------------------------------------------------------------------------
extern "C" void kernel_launch(void* const* d_in, const int* in_sizes, int n_in,
                              void* d_out, int out_size, void* d_ws, size_t ws_size,
                              hipStream_t stream) {
  const float* phi = (const float*)d_in[0];
  const float* wMr = (const float*)d_in[1];
  const float* wMi = (const float*)d_in[2];
  const float* vM  = (const float*)d_in[3];
  const float* W1e = (const float*)d_in[4];
  const float* b1e = (const float*)d_in[5];
  const float* W2e = (const float*)d_in[6];
  const float* b2e = (const float*)d_in[7];
  const float* W1r = (const float*)d_in[8];
  const float* b1r = (const float*)d_in[9];
  const float* W2r = (const float*)d_in[10];
  const float* b2r = (const float*)d_in[11];

  float* out0 = (float*)d_out;            // phi_optimal [B, LS]
  float* out1 = out0 + (size_t)B_ * LS_;  // eta_M^T     [B, LS, M]

  bf16* X     = (bf16*)d_ws;                         // [4096, 5120]
  bf16* W1t   = X + (size_t)ROWS * D_;               // [4096, 5120]
  bf16* h     = W1t + (size_t)N1 * D_;               // [4096, 4096]
  bf16* W2t   = h + (size_t)ROWS * N1;               // [1024, 2048]
  bf16* sfeat = W2t + (size_t)LS_ * H_;              // [256, 2048]
  float* rho  = (float*)(sfeat + (size_t)B_ * 2048); // [4096]

  (void)hipFuncSetAttribute(reinterpret_cast<const void*>(gemm1_256_kernel),
                            hipFuncAttributeMaxDynamicSharedMemorySize, 131072);

  sfeat_kernel<<<(B_ * LS_) / 256, 256, 0, stream>>>(phi, sfeat);
  dim3 tb(32, 8);
  transpose_bf16_kernel<<<dim3(H_ / 32, D_ / 32), tb, 0, stream>>>(W1e, W1t, D_, H_);
  transpose_bf16_kernel<<<dim3(H_ / 32, D_ / 32), tb, 0, stream>>>(W1r, W1t + (size_t)H_ * D_, D_, H_);
  transpose_bf16_kernel<<<dim3(LS_ / 32, H_ / 32), tb, 0, stream>>>(W2e, W2t, H_, LS_);
  build_x_kernel<<<ROWS, 256, 0, stream>>>(sfeat, wMr, wMi, vM, X);

  // GEMM1: 256^2 balanced 4-phase, h = relu(X @ W1t^T + bias), [4096 x 4096], K=5120
  gemm1_256_kernel<<<dim3(N1 / 256, ROWS / 256), 512, 131072, stream>>>(
      X, W1t, b1e, b1r, h);

  // GEMM2: eta_M^T scatter into out1, [4096 x 1024], K=2048
  gemm2_bt_kernel<<<dim3(LS_ / 128, ROWS / 128), 256, 0, stream>>>(
      h, N1, W2t, H_, H_, b2e, out1);

  rho_kernel<<<ROWS, 256, 0, stream>>>(h, W2r, b2r, rho);
  finalize_kernel<<<(B_ * LS_) / 256, 256, 0, stream>>>(phi, rho, out1, out0);
}

// Round 4
// 269.349 us; speedup vs baseline: 3.6335x; 3.6335x over previous
//
#include <hip/hip_runtime.h>
#include <hip/hip_bf16.h>
#include <stdint.h>

// Problem constants
#define B_    256
#define LS_   1024
#define LW_   1024
#define LV_   1024
#define M_    16
#define D_    5120
#define H_    2048
#define ROWS  4096   // B*M
#define N1    4096   // H (eta) + H (rho) fused

typedef __hip_bfloat16 bf16;
typedef __bf16 bf16x8 __attribute__((ext_vector_type(8)));
typedef float f32x4 __attribute__((ext_vector_type(4)));

#define SB0() __builtin_amdgcn_sched_barrier(0)
#define LGKM(n) asm volatile("s_waitcnt lgkmcnt(" #n ")" ::: "memory")
#define VMC(n)  asm volatile("s_waitcnt vmcnt(" #n ")" ::: "memory")

// ---------------------------------------------------------------------------
// async global->LDS, 16B per lane (HW: wave-uniform LDS base + lane*16).
__device__ __forceinline__ void gld_lds16(const void* g, void* l) {
  auto gp = (const __attribute__((address_space(1))) uint32_t*)(uintptr_t)g;
  auto lp = (__attribute__((address_space(3))) uint32_t*)(uint32_t)(uintptr_t)l;
  __builtin_amdgcn_global_load_lds(gp, lp, 16, 0, 0);
}

// ---------------------------------------------------------------------------
__global__ void sfeat_kernel(const float* __restrict__ phi, bf16* __restrict__ sfeat) {
  int i = blockIdx.x * blockDim.x + threadIdx.x;
  int b = i >> 10, l = i & 1023;
  float p = phi[i];
  float s, c;
  sincosf(p, &s, &c);
  sfeat[b * 2048 + l]        = __float2bfloat16(0.03125f * c);
  sfeat[b * 2048 + 1024 + l] = __float2bfloat16(0.03125f * s);
}

// ---------------------------------------------------------------------------
__global__ void transpose_bf16_kernel(const float* __restrict__ in, bf16* __restrict__ out,
                                      int R, int C) {
  __shared__ float tile[32][33];
  int c0 = blockIdx.x * 32, r0 = blockIdx.y * 32;
  int tx = threadIdx.x, ty = threadIdx.y;   // 32 x 8
#pragma unroll
  for (int i = 0; i < 32; i += 8)
    tile[ty + i][tx] = in[(size_t)(r0 + ty + i) * C + (c0 + tx)];
  __syncthreads();
#pragma unroll
  for (int i = 0; i < 32; i += 8)
    out[(size_t)(c0 + ty + i) * R + (r0 + tx)] = __float2bfloat16(tile[tx][ty + i]);
}

// ---------------------------------------------------------------------------
__global__ void build_x_kernel(const bf16* __restrict__ sfeat,
                               const float* __restrict__ wr_, const float* __restrict__ wi_,
                               const float* __restrict__ vM, bf16* __restrict__ X) {
  int row = blockIdx.x;
  int b = row >> 4, m = row & 15;
  bf16* xr = X + (size_t)row * D_;
  const bf16* sf = sfeat + (size_t)b * 2048;
  for (int c = threadIdx.x; c < 2048; c += 256) xr[c] = sf[c];
  const float* wrb = wr_ + (size_t)b * (LW_ * M_) + m;
  for (int c = threadIdx.x; c < 1024; c += 256) xr[2048 + c] = __float2bfloat16(wrb[c * 16]);
  const float* wib = wi_ + (size_t)b * (LW_ * M_) + m;
  for (int c = threadIdx.x; c < 1024; c += 256) xr[3072 + c] = __float2bfloat16(wib[c * 16]);
  for (int c = threadIdx.x; c < 1024; c += 256) xr[4096 + c] = __float2bfloat16(vM[c * 16 + m]);
}

// ---------------------------------------------------------------------------
// GEMM1: 256x256 tile, BK=32, 8 waves (2Mx4N), 4-deep LDS ring, counted
// lgkmcnt pipeline: MFMA on a0-3 overlaps the remaining ds_reads; counted
// vmcnt(4) (never drains mid-loop); ONE barrier per K-tile.
// LDS per buf (32KB): A [256 rows x 32k] 16KB | B 16KB.  Layout: 128B "line"
// = row-pair; 16B slot index within line: slotU=(row&1)*4+kOct, stored at
// slotS = slotU ^ (line&7)  (XOR involution, bank-uniform).
__global__ void __launch_bounds__(512, 2)
gemm1_256_kernel(const bf16* __restrict__ A, const bf16* __restrict__ Bt,
                 const float* __restrict__ bias0, const float* __restrict__ bias1,
                 bf16* __restrict__ outH) {
  extern __shared__ __align__(16) char smem[];
  constexpr int NT = D_ / 32;   // 160 K-tiles

  const int tid  = threadIdx.x;
  const int lane = tid & 63;
  const int wave = tid >> 6;
  const int wr = wave >> 2, wc = wave & 3;   // 2 x 4 wave grid, wave-tile 128x64
  const int fr = lane & 15, fq = lane >> 4;
  const int row0 = blockIdx.y * 256, col0 = blockIdx.x * 256;

  // fragment ds_read lane statics (row = ...*16 + fr, kOct = fq)
  const int slotF = (((fr & 1) << 2) | fq) ^ ((fr >> 1) & 7);
  const int aOff = (wr << 13) + ((fr >> 1) << 7) + (slotF << 4);           // + m*1024
  const int bOff = 16384 + (wc << 12) + ((fr >> 1) << 7) + (slotF << 4);   // + n*1024

  // staging lane statics (two 8KB halves p=0,1 per operand)
  const int lg0 = (tid >> 3), lg1 = 64 + (tid >> 3);
  const int su0 = (tid & 7) ^ (lg0 & 7), su1 = (tid & 7) ^ (lg1 & 7);
  const int rowp0 = lg0 * 2 + (su0 >> 2), rowp1 = lg1 * 2 + (su1 >> 2);
  const int kb0 = (su0 & 3) << 4, kb1 = (su1 & 3) << 4;
  const char* pA0 = (const char*)A  + (size_t)(row0 + rowp0) * (D_ * 2) + kb0;
  const char* pA1 = (const char*)A  + (size_t)(row0 + rowp1) * (D_ * 2) + kb1;
  const char* pB0 = (const char*)Bt + (size_t)(col0 + rowp0) * (D_ * 2) + kb0;
  const char* pB1 = (const char*)Bt + (size_t)(col0 + rowp1) * (D_ * 2) + kb1;

  auto stageTile = [&](int T) {   // 4 gld per wave (vmcnt +4)
    char* dst = smem + (size_t)(T & 3) * 32768;
    const size_t ko = (size_t)T * 64;
    gld_lds16(pA0 + ko, dst + 0     + tid * 16);
    gld_lds16(pA1 + ko, dst + 8192  + tid * 16);
    gld_lds16(pB0 + ko, dst + 16384 + tid * 16);
    gld_lds16(pB1 + ko, dst + 24576 + tid * 16);
  };

  f32x4 acc[8][4] = {};
  bf16x8 bA[4], bB[4];

  // prologue: stage tiles 0,1,2; retire 0,1 (keep 2 flying); pre-read B(t0)
  stageTile(0); stageTile(1); stageTile(2);
  VMC(4);
  __builtin_amdgcn_s_barrier();
  {
    const char* bP = smem + bOff;   // buf0 B
#pragma unroll
    for (int n = 0; n < 4; ++n) bA[n] = *(const bf16x8*)(bP + n * 1024);
  }
  SB0();

  // steady iteration: reads a(T) + b(T+1); stage T+3; counted waits; 1 barrier
  auto doIter = [&](int T, bf16x8 (&bCur)[4], bf16x8 (&bNxt)[4]) {
    const char* aP = smem + (size_t)(T & 3) * 32768 + aOff;
    const char* bP = smem + (size_t)((T + 1) & 3) * 32768 + bOff;
    bf16x8 a[8];
#pragma unroll
    for (int m = 0; m < 4; ++m) a[m] = *(const bf16x8*)(aP + m * 1024);
    SB0();
#pragma unroll
    for (int m = 4; m < 8; ++m) a[m] = *(const bf16x8*)(aP + m * 1024);
    SB0();
#pragma unroll
    for (int n = 0; n < 4; ++n) bNxt[n] = *(const bf16x8*)(bP + n * 1024);
    SB0();
    if (T + 3 < NT) stageTile(T + 3);
    SB0();
    LGKM(8);                     // a0-3 landed; a4-7 + bNxt still in flight
    SB0();
    __builtin_amdgcn_s_setprio(1);
#pragma unroll
    for (int m = 0; m < 4; ++m)
#pragma unroll
      for (int n = 0; n < 4; ++n)
        acc[m][n] = __builtin_amdgcn_mfma_f32_16x16x32_bf16(a[m], bCur[n], acc[m][n], 0, 0, 0);
    SB0();
    LGKM(4);                     // a4-7 landed; bNxt may still fly
    SB0();
#pragma unroll
    for (int m = 4; m < 8; ++m)
#pragma unroll
      for (int n = 0; n < 4; ++n)
        acc[m][n] = __builtin_amdgcn_mfma_f32_16x16x32_bf16(a[m], bCur[n], acc[m][n], 0, 0, 0);
    __builtin_amdgcn_s_setprio(0);
    SB0();
    LGKM(0);                     // bNxt in regs (issued long ago — cheap)
    if (T + 3 < NT) { VMC(4); }  // retire tile T+2 (keep T+3 flying)
    else            { VMC(0); }  // tail drain
    __builtin_amdgcn_s_barrier();
  };

  for (int t = 0; t < NT - 2; t += 2) {
    doIter(t,     bA, bB);
    doIter(t + 1, bB, bA);
  }
  doIter(NT - 2, bA, bB);        // t=158 (reads B of 159 into bB)

  // final tile t=159: no next-B read, no staging
  {
    const char* aP = smem + (size_t)((NT - 1) & 3) * 32768 + aOff;
    bf16x8 a[8];
#pragma unroll
    for (int m = 0; m < 4; ++m) a[m] = *(const bf16x8*)(aP + m * 1024);
    SB0();
#pragma unroll
    for (int m = 4; m < 8; ++m) a[m] = *(const bf16x8*)(aP + m * 1024);
    SB0();
    LGKM(4);
    SB0();
    __builtin_amdgcn_s_setprio(1);
#pragma unroll
    for (int m = 0; m < 4; ++m)
#pragma unroll
      for (int n = 0; n < 4; ++n)
        acc[m][n] = __builtin_amdgcn_mfma_f32_16x16x32_bf16(a[m], bB[n], acc[m][n], 0, 0, 0);
    SB0();
    LGKM(0);
    SB0();
#pragma unroll
    for (int m = 4; m < 8; ++m)
#pragma unroll
      for (int n = 0; n < 4; ++n)
        acc[m][n] = __builtin_amdgcn_mfma_f32_16x16x32_bf16(a[m], bB[n], acc[m][n], 0, 0, 0);
    __builtin_amdgcn_s_setprio(0);
  }

  // epilogue: bias + relu -> bf16
#pragma unroll
  for (int m = 0; m < 8; ++m) {
#pragma unroll
    for (int n = 0; n < 4; ++n) {
      const int c = col0 + wc * 64 + n * 16 + fr;
      const float bias = (c < H_) ? bias0[c] : bias1[c - H_];
#pragma unroll
      for (int j = 0; j < 4; ++j) {
        const int r = row0 + wr * 128 + m * 16 + fq * 4 + j;
        float v = acc[m][n][j] + bias;
        outH[(size_t)r * N1 + c] = __float2bfloat16(v > 0.f ? v : 0.f);
      }
    }
  }
}

// ---------------------------------------------------------------------------
// 128x128 m97-style GEMM (GEMM2): out1 scatter = eta_M^T
__global__ void __launch_bounds__(256)
gemm2_bt_kernel(const bf16* __restrict__ A, int lda,
                const bf16* __restrict__ Bt, int ldb, int K,
                const float* __restrict__ bias0, float* __restrict__ outS) {
  __shared__ __align__(16) bf16 As[128 * 32];
  __shared__ __align__(16) bf16 Bs[128 * 32];

  const int tid  = threadIdx.x;
  const int lane = tid & 63;
  const int wave = tid >> 6;
  const int wr = wave >> 1, wc = wave & 1;
  const int fr = lane & 15;
  const int fq = lane >> 4;
  const int row0 = blockIdx.y * 128;
  const int col0 = blockIdx.x * 128;

  const int li0 = tid, li1 = tid + 256;
  const int r0s = li0 >> 2, c0s = (li0 & 3) << 3;
  const int r1s = li1 >> 2, c1s = (li1 & 3) << 3;

  f32x4 acc[4][4] = {};

  for (int k0 = 0; k0 < K; k0 += 32) {
    gld_lds16(A  + (size_t)(row0 + r0s) * lda + k0 + c0s, &As[li0 * 8]);
    gld_lds16(Bt + (size_t)(col0 + r0s) * ldb + k0 + c0s, &Bs[li0 * 8]);
    gld_lds16(A  + (size_t)(row0 + r1s) * lda + k0 + c1s, &As[li1 * 8]);
    gld_lds16(Bt + (size_t)(col0 + r1s) * ldb + k0 + c1s, &Bs[li1 * 8]);
    __syncthreads();

    bf16x8 a[4], b[4];
#pragma unroll
    for (int m = 0; m < 4; ++m)
      a[m] = *reinterpret_cast<const bf16x8*>(&As[(wr * 64 + m * 16 + fr) * 32 + fq * 8]);
#pragma unroll
    for (int n = 0; n < 4; ++n)
      b[n] = *reinterpret_cast<const bf16x8*>(&Bs[(wc * 64 + n * 16 + fr) * 32 + fq * 8]);
#pragma unroll
    for (int m = 0; m < 4; ++m)
#pragma unroll
      for (int n = 0; n < 4; ++n)
        acc[m][n] = __builtin_amdgcn_mfma_f32_16x16x32_bf16(a[m], b[n], acc[m][n], 0, 0, 0);
    __syncthreads();
  }

#pragma unroll
  for (int m = 0; m < 4; ++m) {
#pragma unroll
    for (int n = 0; n < 4; ++n) {
      const int c = col0 + wc * 64 + n * 16 + fr;
      const float bias = bias0[c];
#pragma unroll
      for (int j = 0; j < 4; ++j) {
        const int r = row0 + wr * 64 + m * 16 + fq * 4 + j;
        outS[((size_t)(r >> 4)) * (LS_ * M_) + (size_t)c * M_ + (r & 15)] = acc[m][n][j] + bias;
      }
    }
  }
}

// ---------------------------------------------------------------------------
__global__ void rho_kernel(const bf16* __restrict__ h, const float* __restrict__ w2r,
                           const float* __restrict__ b2r, float* __restrict__ rho) {
  int r = blockIdx.x;
  int t = threadIdx.x;
  int lane = t & 63, wave = t >> 6;
  const bf16* hr = h + (size_t)r * N1 + H_;
  float s = 0.f;
#pragma unroll
  for (int j = 0; j < 8; ++j)
    s += __bfloat162float(hr[t * 8 + j]) * w2r[t * 8 + j];
#pragma unroll
  for (int off = 32; off > 0; off >>= 1) s += __shfl_down(s, off);
  __shared__ float ws4[4];
  if (lane == 0) ws4[wave] = s;
  __syncthreads();
  if (t == 0) rho[r] = ws4[0] + ws4[1] + ws4[2] + ws4[3] + b2r[0];
}

// ---------------------------------------------------------------------------
__global__ void finalize_kernel(const float* __restrict__ phi, const float* __restrict__ rho,
                                const float* __restrict__ etaMT, float* __restrict__ out0) {
  int i = blockIdx.x * blockDim.x + threadIdx.x;
  int b = i >> 10;
  const float* em = etaMT + (size_t)i * 16;
  const float* rb = rho + b * 16;
  float s = 0.f;
#pragma unroll
  for (int m = 0; m < 16; ++m) s += rb[m] * em[m];
  out0[i] = phi[i] - s;
}

// ---------------------------------------------------------------------------
extern "C" void kernel_launch(void* const* d_in, const int* in_sizes, int n_in,
                              void* d_out, int out_size, void* d_ws, size_t ws_size,
                              hipStream_t stream) {
  const float* phi = (const float*)d_in[0];
  const float* wMr = (const float*)d_in[1];
  const float* wMi = (const float*)d_in[2];
  const float* vM  = (const float*)d_in[3];
  const float* W1e = (const float*)d_in[4];
  const float* b1e = (const float*)d_in[5];
  const float* W2e = (const float*)d_in[6];
  const float* b2e = (const float*)d_in[7];
  const float* W1r = (const float*)d_in[8];
  const float* b1r = (const float*)d_in[9];
  const float* W2r = (const float*)d_in[10];
  const float* b2r = (const float*)d_in[11];

  float* out0 = (float*)d_out;            // phi_optimal [B, LS]
  float* out1 = out0 + (size_t)B_ * LS_;  // eta_M^T     [B, LS, M]

  bf16* X     = (bf16*)d_ws;                         // [4096, 5120]
  bf16* W1t   = X + (size_t)ROWS * D_;               // [4096, 5120]
  bf16* h     = W1t + (size_t)N1 * D_;               // [4096, 4096]
  bf16* W2t   = h + (size_t)ROWS * N1;               // [1024, 2048]
  bf16* sfeat = W2t + (size_t)LS_ * H_;              // [256, 2048]
  float* rho  = (float*)(sfeat + (size_t)B_ * 2048); // [4096]

  (void)hipFuncSetAttribute(reinterpret_cast<const void*>(gemm1_256_kernel),
                            hipFuncAttributeMaxDynamicSharedMemorySize, 131072);

  sfeat_kernel<<<(B_ * LS_) / 256, 256, 0, stream>>>(phi, sfeat);
  dim3 tb(32, 8);
  transpose_bf16_kernel<<<dim3(H_ / 32, D_ / 32), tb, 0, stream>>>(W1e, W1t, D_, H_);
  transpose_bf16_kernel<<<dim3(H_ / 32, D_ / 32), tb, 0, stream>>>(W1r, W1t + (size_t)H_ * D_, D_, H_);
  transpose_bf16_kernel<<<dim3(LS_ / 32, H_ / 32), tb, 0, stream>>>(W2e, W2t, H_, LS_);
  build_x_kernel<<<ROWS, 256, 0, stream>>>(sfeat, wMr, wMi, vM, X);

  // GEMM1: 256^2, BK=32, 4-deep ring, counted-waitcnt pipeline
  gemm1_256_kernel<<<dim3(N1 / 256, ROWS / 256), 512, 131072, stream>>>(
      X, W1t, b1e, b1r, h);

  // GEMM2: eta_M^T scatter into out1, [4096 x 1024], K=2048
  gemm2_bt_kernel<<<dim3(LS_ / 128, ROWS / 128), 256, 0, stream>>>(
      h, N1, W2t, H_, H_, b2e, out1);

  rho_kernel<<<ROWS, 256, 0, stream>>>(h, W2r, b2r, rho);
  finalize_kernel<<<(B_ * LS_) / 256, 256, 0, stream>>>(phi, rho, out1, out0);
}